// Round 8
// baseline (461.424 us; speedup 1.0000x reference)
//
#include <hip/hip_runtime.h>
#include <hip/hip_bf16.h>
#include <stdint.h>

#define EPS 1e-3f

typedef __attribute__((ext_vector_type(8))) short bf16x8;
typedef __attribute__((ext_vector_type(4))) float f32x4;

__device__ inline uint32_t pk2(float a, float b) {
    __hip_bfloat162 p;
    p.x = __float2bfloat16(a);
    p.y = __float2bfloat16(b);
    return *(uint32_t*)&p;
}

// ---------------------------------------------------------------------------
// k0a: small preps.
//  W1t[f][K'] = bf16(W1[c][k*64+f]),  K' = k*64+c           (12288 elems)
//  Abf[(kb*64+fo)*8+j] = bf16(Wt[dt][fi][fo]), kb*8+j=dt*64+fi (36864 elems)
//  csA_g[k][t*25+w] = sum_v A[k][t][v][w]                    (22500 floats)
// ---------------------------------------------------------------------------
__global__ __launch_bounds__(256) void k0_prep_small(
    const float* __restrict__ W1, const float* __restrict__ Wt,
    const float* __restrict__ A,
    uint16_t* __restrict__ W1t, uint16_t* __restrict__ Abf,
    float* __restrict__ csA_g)
{
    int i = blockIdx.x * 256 + threadIdx.x;
    if (i < 12288) {
        int f = i / 192, Kp = i % 192, k = Kp >> 6, c = Kp & 63;
        __hip_bfloat16 b = __float2bfloat16(W1[c * 192 + k * 64 + f]);
        W1t[i] = *(uint16_t*)&b;
    } else if (i < 49152) {
        int j = i - 12288;
        int jj = j & 7, fo = (j >> 3) & 63, kb = j >> 9;
        int kk = kb * 8 + jj, dt = kk >> 6, fi = kk & 63;
        __hip_bfloat16 b = __float2bfloat16(Wt[(dt * 64 + fi) * 64 + fo]);
        Abf[j] = *(uint16_t*)&b;
    } else if (i < 71652) {
        int j = i - 49152;
        int k = j / 7500, r = j % 7500;
        int t = r / 25, w = r % 25;
        float s = 0.f;
        for (int v = 0; v < 25; ++v)
            s += A[((k * 300 + t) * 25 + v) * 25 + w];
        csA_g[j] = s;
    }
}

// ---------------------------------------------------------------------------
// k0b: At_g[k][t][w32][v32] = bf16(A[k][t][v][w]), zero outside v<25,w<25.
// ---------------------------------------------------------------------------
__global__ __launch_bounds__(256) void k0_prep_At(
    const float* __restrict__ A, uint16_t* __restrict__ At_g)
{
    int i = blockIdx.x * 256 + threadIdx.x;
    if (i < 921600) {
        int v = i & 31, w = (i >> 5) & 31, rest = i >> 10;
        int t = rest % 300, k = rest / 300;
        float val = 0.f;
        if (v < 25 && w < 25)
            val = A[((k * 300 + t) * 25 + v) * 25 + w];
        __hip_bfloat16 b = __float2bfloat16(val);
        At_g[i] = *(uint16_t*)&b;
    }
}

// ---------------------------------------------------------------------------
// k0c: x [n][c][t][v] fp32 -> xf bf16 pre-packed MFMA A-frag layout:
//   xf u32 idx = (n*300+t)*768 + ((mf*3+g)*16+l15)*4 + jp   (g<3; v=g*8+jp*2)
//   x24[(n*300+t)*64 + c] = bf16(x[n][c][t][24])
// One block per (n, 10-t chunk). LDS transpose, all global I/O coalesced.
// ---------------------------------------------------------------------------
__global__ __launch_bounds__(256) void k0_prep_x(
    const float* __restrict__ x, uint32_t* __restrict__ xfu,
    uint16_t* __restrict__ x24)
{
    __shared__ uint16_t lds[64 * 252];
    const int t0  = blockIdx.x * 10;
    const int n   = blockIdx.y;
    const int tid = threadIdx.x;
    const float* xb = x + (size_t)n * 480000 + t0 * 25;

    // read 250 floats per channel (float2, 8B-aligned since t0*25 is even)
    for (int i = tid; i < 8000; i += 256) {
        int c = i / 125, r2 = i - c * 125;
        float2 f2 = *(const float2*)(xb + (size_t)c * 7500 + r2 * 2);
        *(uint32_t*)&lds[c * 252 + r2 * 2] = pk2(f2.x, f2.y);
    }
    __syncthreads();

    const uint32_t obase = (uint32_t)(n * 300 + t0) * 768;
    for (int o = tid; o < 7680; o += 256) {
        int trel = o / 768, r = o - trel * 768;
        int jp = r & 3, l15 = (r >> 2) & 15, q = r >> 6;
        int gg = q % 3, mf = q / 3;
        int c  = l15 + 16 * mf;
        int rr = trel * 25 + gg * 8 + jp * 2;       // may be odd: combine u16s
        uint32_t val = (uint32_t)lds[c * 252 + rr]
                     | ((uint32_t)lds[c * 252 + rr + 1] << 16);
        xfu[obase + trel * 768 + r] = val;
    }
    for (int i = tid; i < 640; i += 256) {
        int trel = i >> 6, c = i & 63;
        x24[(uint32_t)(n * 300 + t0 + trel) * 64 + c] = lds[c * 252 + trel * 25 + 24];
    }
}

// ---------------------------------------------------------------------------
// k1 xf-variant: t-tile 4, 4 waves, 39,680 B LDS -> 4 blocks/CU.
//  A-frags: 3 x dwordx4 (xf) + 1 u16 (x24) per lane -- fully coalesced.
// ---------------------------------------------------------------------------
#define K1_SMEM 39680
__global__ __launch_bounds__(256, 4) void k1_fused_xf(
    const char* __restrict__ xfb, const uint16_t* __restrict__ x24,
    const uint16_t* __restrict__ At_g,
    const uint16_t* __restrict__ W1t, const float* __restrict__ csA_g,
    const float* __restrict__ b1,
    const float* __restrict__ gamma1, const float* __restrict__ beta1,
    const float* __restrict__ mean1, const float* __restrict__ var1,
    uint32_t* __restrict__ h2u)
{
    extern __shared__ __align__(16) char smem[];
    float* s1s   = (float*)(smem + 38400);
    float* b1ns  = (float*)(smem + 38656);
    float* b1s   = (float*)(smem + 38912);

    const int t0   = blockIdx.x * 4;
    const int n    = blockIdx.y;
    const int tid  = threadIdx.x;
    const int lane = tid & 63, wv = tid >> 6;
    const int l15  = lane & 15, g = lane >> 4;
    const int t    = t0 + wv;

    // ---- B-frags for GEMM-u ----
    bf16x8 bfr[6];
    #pragma unroll
    for (int nf = 0; nf < 6; ++nf) {
        const int col = nf * 16 + l15;
        const int k = col >> 5, w = col & 31;
        bfr[nf] = *(const bf16x8*)(At_g + (((k * 300 + t) * 32 + w) * 32 + g * 8));
    }

    // ---- A-frags from xf / x24 ----
    const uint32_t xoff = (uint32_t)(n * 300 + t) * 3072;
    bf16x8 a[4];
    #pragma unroll
    for (int mf = 0; mf < 4; ++mf) {
        union { bf16x8 v; uint32_t u[4]; } ua;
        if (g < 3) {
            ua.v = *(const bf16x8*)(xfb + xoff + (((mf * 3 + g) * 16 + l15) << 4));
        } else {
            ua.u[0] = (uint32_t)x24[(uint32_t)(n * 300 + t) * 64 + l15 + 16 * mf];
            ua.u[1] = 0; ua.u[2] = 0; ua.u[3] = 0;
        }
        a[mf] = ua.v;
    }

    // ---- epilogue constants ----
    if (tid < 64) {
        float rs = rsqrtf(var1[tid] + EPS);
        s1s[tid]  = gamma1[tid] * rs;
        b1ns[tid] = beta1[tid] - gamma1[tid] * mean1[tid] * rs;
    }
    if (tid >= 64 && tid < 256) b1s[tid - 64] = b1[tid - 64];

    // ---- GEMM-u ----
    f32x4 acc[4][6];
    #pragma unroll
    for (int mf = 0; mf < 4; ++mf)
        #pragma unroll
        for (int nf = 0; nf < 6; ++nf)
            acc[mf][nf] = (f32x4){0.f, 0.f, 0.f, 0.f};

    #pragma unroll
    for (int nf = 0; nf < 6; ++nf) {
        acc[0][nf] = __builtin_amdgcn_mfma_f32_16x16x32_bf16(a[0], bfr[nf], acc[0][nf], 0, 0, 0);
        acc[1][nf] = __builtin_amdgcn_mfma_f32_16x16x32_bf16(a[1], bfr[nf], acc[1][nf], 0, 0, 0);
        acc[2][nf] = __builtin_amdgcn_mfma_f32_16x16x32_bf16(a[2], bfr[nf], acc[2][nf], 0, 0, 0);
        acc[3][nf] = __builtin_amdgcn_mfma_f32_16x16x32_bf16(a[3], bfr[nf], acc[3][nf], 0, 0, 0);
    }

    // ---- write U rows (colrow = wv*25+w), swizzled ----
    #pragma unroll
    for (int nf = 0; nf < 6; ++nf) {
        const int col = nf * 16 + l15;
        const int k = col >> 5, w = col & 31;
        if (w < 25) {
            const int colrow = wv * 25 + w;
            const int sw = (w & 7) << 4;
            #pragma unroll
            for (int mf = 0; mf < 4; ++mf) {
                const int c0 = mf * 16 + g * 4;
                const int off = colrow * 384 + (((k * 64 + c0) * 2) ^ sw);
                uint2 val;
                val.x = pk2(acc[mf][nf][0], acc[mf][nf][1]);
                val.y = pk2(acc[mf][nf][2], acc[mf][nf][3]);
                *(uint2*)(smem + off) = val;
            }
        }
    }
    __syncthreads();

    // ---- GEMM-z ----
    int colv[2], coladdr[2], swz[2];
    const int nq = (wv < 3) ? 2 : 1;
    #pragma unroll
    for (int q = 0; q < 2; ++q) {
        int fr  = wv + 4 * q;
        int col = fr * 16 + l15;
        colv[q] = col;
        int colc = (col < 100) ? col : 99;
        coladdr[q] = colc * 384;
        swz[q] = ((colc % 25) & 7) << 4;
    }

    f32x4 accz[4][2];
    #pragma unroll
    for (int mf = 0; mf < 4; ++mf)
        #pragma unroll
        for (int q = 0; q < 2; ++q)
            accz[mf][q] = (f32x4){0.f, 0.f, 0.f, 0.f};

    #pragma unroll
    for (int kb = 0; kb < 6; ++kb) {
        bf16x8 az[4];
        #pragma unroll
        for (int mf = 0; mf < 4; ++mf)
            az[mf] = *(const bf16x8*)(W1t + (l15 + 16 * mf) * 192 + kb * 32 + g * 8);
        #pragma unroll
        for (int q = 0; q < 2; ++q) {
            if (q < nq) {
                bf16x8 b = *(const bf16x8*)(smem + coladdr[q] + ((kb * 64 + g * 16) ^ swz[q]));
                accz[0][q] = __builtin_amdgcn_mfma_f32_16x16x32_bf16(az[0], b, accz[0][q], 0, 0, 0);
                accz[1][q] = __builtin_amdgcn_mfma_f32_16x16x32_bf16(az[1], b, accz[1][q], 0, 0, 0);
                accz[2][q] = __builtin_amdgcn_mfma_f32_16x16x32_bf16(az[2], b, accz[2][q], 0, 0, 0);
                accz[3][q] = __builtin_amdgcn_mfma_f32_16x16x32_bf16(az[3], b, accz[3][q], 0, 0, 0);
            }
        }
    }

    // ---- epilogue ----
    const uint32_t hbase = (uint32_t)(n * 300 + t0) * 800;
    const int csbase = t0 * 25;
    #pragma unroll
    for (int q = 0; q < 2; ++q) {
        if (q < nq) {
            const int col = colv[q];
            if (col < 100) {
                const int trel = col / 25, w = col - trel * 25;
                const float cs0 = csA_g[csbase + col];
                const float cs1 = csA_g[7500 + csbase + col];
                const float cs2 = csA_g[15000 + csbase + col];
                const uint32_t rowbase = hbase + trel * 800 + w * 32;
                #pragma unroll
                for (int mf = 0; mf < 4; ++mf) {
                    const int f0 = mf * 16 + g * 4;
                    float zz[4];
                    #pragma unroll
                    for (int rg = 0; rg < 4; ++rg) {
                        const int f = f0 + rg;
                        float z = accz[mf][q][rg]
                                + b1s[f] * cs0 + b1s[64 + f] * cs1 + b1s[128 + f] * cs2;
                        z = z * s1s[f] + b1ns[f];
                        zz[rg] = fmaxf(z, 0.f);
                    }
                    uint2 st;
                    st.x = pk2(zz[0], zz[1]);
                    st.y = pk2(zz[2], zz[3]);
                    *(uint2*)(h2u + rowbase + (f0 >> 1)) = st;
                }
            }
        }
    }
}

// ---------------------------------------------------------------------------
// k1 fallback (R7 exact): direct x gather. Used only if ws too small for xf.
// ---------------------------------------------------------------------------
__global__ __launch_bounds__(256, 4) void k1_fused(
    const float* __restrict__ x, const uint16_t* __restrict__ At_g,
    const uint16_t* __restrict__ W1t, const float* __restrict__ csA_g,
    const float* __restrict__ b1,
    const float* __restrict__ gamma1, const float* __restrict__ beta1,
    const float* __restrict__ mean1, const float* __restrict__ var1,
    uint32_t* __restrict__ h2u)
{
    extern __shared__ __align__(16) char smem[];
    float* s1s   = (float*)(smem + 38400);
    float* b1ns  = (float*)(smem + 38656);
    float* b1s   = (float*)(smem + 38912);

    const int t0   = blockIdx.x * 4;
    const int n    = blockIdx.y;
    const int tid  = threadIdx.x;
    const int lane = tid & 63, wv = tid >> 6;
    const int l15  = lane & 15, g = lane >> 4;
    const int t    = t0 + wv;

    bf16x8 bfr[6];
    #pragma unroll
    for (int nf = 0; nf < 6; ++nf) {
        const int col = nf * 16 + l15;
        const int k = col >> 5, w = col & 31;
        bfr[nf] = *(const bf16x8*)(At_g + (((k * 300 + t) * 32 + w) * 32 + g * 8));
    }

    const float* xb = x + (size_t)n * 480000 + t * 25;
    bf16x8 a[4];
    #pragma unroll
    for (int mf = 0; mf < 4; ++mf) {
        const int c = l15 + 16 * mf;
        const float* xr = xb + (size_t)c * 7500;
        union { bf16x8 v; uint32_t u[4]; } ua;
        if (g < 3) {
            const float* p = xr + g * 8;
            ua.u[0] = pk2(p[0], p[1]);
            ua.u[1] = pk2(p[2], p[3]);
            ua.u[2] = pk2(p[4], p[5]);
            ua.u[3] = pk2(p[6], p[7]);
        } else {
            ua.u[0] = pk2(xr[24], 0.f);
            ua.u[1] = 0; ua.u[2] = 0; ua.u[3] = 0;
        }
        a[mf] = ua.v;
    }

    if (tid < 64) {
        float rs = rsqrtf(var1[tid] + EPS);
        s1s[tid]  = gamma1[tid] * rs;
        b1ns[tid] = beta1[tid] - gamma1[tid] * mean1[tid] * rs;
    }
    if (tid >= 64 && tid < 256) b1s[tid - 64] = b1[tid - 64];

    f32x4 acc[4][6];
    #pragma unroll
    for (int mf = 0; mf < 4; ++mf)
        #pragma unroll
        for (int nf = 0; nf < 6; ++nf)
            acc[mf][nf] = (f32x4){0.f, 0.f, 0.f, 0.f};

    #pragma unroll
    for (int nf = 0; nf < 6; ++nf) {
        acc[0][nf] = __builtin_amdgcn_mfma_f32_16x16x32_bf16(a[0], bfr[nf], acc[0][nf], 0, 0, 0);
        acc[1][nf] = __builtin_amdgcn_mfma_f32_16x16x32_bf16(a[1], bfr[nf], acc[1][nf], 0, 0, 0);
        acc[2][nf] = __builtin_amdgcn_mfma_f32_16x16x32_bf16(a[2], bfr[nf], acc[2][nf], 0, 0, 0);
        acc[3][nf] = __builtin_amdgcn_mfma_f32_16x16x32_bf16(a[3], bfr[nf], acc[3][nf], 0, 0, 0);
    }

    #pragma unroll
    for (int nf = 0; nf < 6; ++nf) {
        const int col = nf * 16 + l15;
        const int k = col >> 5, w = col & 31;
        if (w < 25) {
            const int colrow = wv * 25 + w;
            const int sw = (w & 7) << 4;
            #pragma unroll
            for (int mf = 0; mf < 4; ++mf) {
                const int c0 = mf * 16 + g * 4;
                const int off = colrow * 384 + (((k * 64 + c0) * 2) ^ sw);
                uint2 val;
                val.x = pk2(acc[mf][nf][0], acc[mf][nf][1]);
                val.y = pk2(acc[mf][nf][2], acc[mf][nf][3]);
                *(uint2*)(smem + off) = val;
            }
        }
    }
    __syncthreads();

    int colv[2], coladdr[2], swz[2];
    const int nq = (wv < 3) ? 2 : 1;
    #pragma unroll
    for (int q = 0; q < 2; ++q) {
        int fr  = wv + 4 * q;
        int col = fr * 16 + l15;
        colv[q] = col;
        int colc = (col < 100) ? col : 99;
        coladdr[q] = colc * 384;
        swz[q] = ((colc % 25) & 7) << 4;
    }

    f32x4 accz[4][2];
    #pragma unroll
    for (int mf = 0; mf < 4; ++mf)
        #pragma unroll
        for (int q = 0; q < 2; ++q)
            accz[mf][q] = (f32x4){0.f, 0.f, 0.f, 0.f};

    #pragma unroll
    for (int kb = 0; kb < 6; ++kb) {
        bf16x8 az[4];
        #pragma unroll
        for (int mf = 0; mf < 4; ++mf)
            az[mf] = *(const bf16x8*)(W1t + (l15 + 16 * mf) * 192 + kb * 32 + g * 8);
        #pragma unroll
        for (int q = 0; q < 2; ++q) {
            if (q < nq) {
                bf16x8 b = *(const bf16x8*)(smem + coladdr[q] + ((kb * 64 + g * 16) ^ swz[q]));
                accz[0][q] = __builtin_amdgcn_mfma_f32_16x16x32_bf16(az[0], b, accz[0][q], 0, 0, 0);
                accz[1][q] = __builtin_amdgcn_mfma_f32_16x16x32_bf16(az[1], b, accz[1][q], 0, 0, 0);
                accz[2][q] = __builtin_amdgcn_mfma_f32_16x16x32_bf16(az[2], b, accz[2][q], 0, 0, 0);
                accz[3][q] = __builtin_amdgcn_mfma_f32_16x16x32_bf16(az[3], b, accz[3][q], 0, 0, 0);
            }
        }
    }

    const uint32_t hbase = (uint32_t)(n * 300 + t0) * 800;
    const int csbase = t0 * 25;
    #pragma unroll
    for (int q = 0; q < 2; ++q) {
        if (q < nq) {
            const int col = colv[q];
            if (col < 100) {
                const int trel = col / 25, w = col - trel * 25;
                const float cs0 = csA_g[csbase + col];
                const float cs1 = csA_g[7500 + csbase + col];
                const float cs2 = csA_g[15000 + csbase + col];
                const uint32_t rowbase = hbase + trel * 800 + w * 32;
                #pragma unroll
                for (int mf = 0; mf < 4; ++mf) {
                    const int f0 = mf * 16 + g * 4;
                    float zz[4];
                    #pragma unroll
                    for (int rg = 0; rg < 4; ++rg) {
                        const int f = f0 + rg;
                        float z = accz[mf][q][rg]
                                + b1s[f] * cs0 + b1s[64 + f] * cs1 + b1s[128 + f] * cs2;
                        z = z * s1s[f] + b1ns[f];
                        zz[rg] = fmaxf(z, 0.f);
                    }
                    uint2 st;
                    st.x = pk2(zz[0], zz[1]);
                    st.y = pk2(zz[2], zz[3]);
                    *(uint2*)(h2u + rowbase + (f0 >> 1)) = st;
                }
            }
        }
    }
}

// ---------------------------------------------------------------------------
// k2: operand-swapped temporal conv GEMM (unchanged from R7).
// ---------------------------------------------------------------------------
#define K2_SMEM 51712
__global__ __launch_bounds__(256, 3) void k2_mfma(
    const char* __restrict__ h2b,
    const uint16_t* __restrict__ Abf,
    const float* __restrict__ bt,
    const float* __restrict__ gamma2, const float* __restrict__ beta2,
    const float* __restrict__ mean2,  const float* __restrict__ var2,
    const float* __restrict__ x,
    float* __restrict__ out)
{
    extern __shared__ __align__(16) char smem2[];
    char*  lds_h = smem2;
    float* s2s   = (float*)(smem2 + 51200);
    float* b2s   = s2s + 64;

    const int t0  = blockIdx.x * 8;
    const int n   = blockIdx.y;
    const int tid = threadIdx.x;

    if (tid < 64) {
        float rs = rsqrtf(var2[tid] + EPS);
        float s  = gamma2[tid] * rs;
        s2s[tid] = s;
        b2s[tid] = beta2[tid] - gamma2[tid] * mean2[tid] * rs + bt[tid] * s;
    }

    const size_t hn = (size_t)n * 300 * 3200;
    for (int c = tid; c < 3200; c += 256) {
        int rr = c >> 3, c8 = c & 7;
        int trow = rr / 25;
        int w = rr - trow * 25;
        int tg = t0 - 4 + trow;
        int4 v = make_int4(0, 0, 0, 0);
        if (tg >= 0 && tg < 300)
            v = *(const int4*)(h2b + hn + (size_t)tg * 3200 + w * 128 + (c8 << 4));
        int s = c << 4;
        *(int4*)(lds_h + (s ^ (((s >> 7) & 7) << 4))) = v;
    }
    __syncthreads();

    const int wv = tid >> 6, lane = tid & 63;
    const int l15 = lane & 15, g = lane >> 4;
    const int nMf = (wv == 0) ? 4 : 3;

    int rbase[4];
    #pragma unroll
    for (int q = 0; q < 4; ++q) {
        int col = (q * 4 + wv) * 16 + l15;
        rbase[q] = (col < 200) ? col : 199;
    }

    f32x4 acc[4][4];
    #pragma unroll
    for (int q = 0; q < 4; ++q)
        #pragma unroll
        for (int mf = 0; mf < 4; ++mf)
            acc[q][mf] = (f32x4){0.f, 0.f, 0.f, 0.f};

    for (int kk = 0; kk < 18; ++kk) {
        const int dt   = kk >> 1;
        const int half = (kk & 1) << 6;
        const int kb   = kk * 4 + g;
        bf16x8 wfr[4];
        #pragma unroll
        for (int mf = 0; mf < 4; ++mf)
            wfr[mf] = *(const bf16x8*)(Abf + (kb * 64 + l15 + mf * 16) * 8);
        #pragma unroll
        for (int q = 0; q < 4; ++q) {
            if (q < nMf) {
                int r = rbase[q] + 25 * dt;
                int s = (r << 7) + half + (g << 4);
                bf16x8 hfr = *(const bf16x8*)(lds_h + (s ^ ((r & 7) << 4)));
                acc[q][0] = __builtin_amdgcn_mfma_f32_16x16x32_bf16(hfr, wfr[0], acc[q][0], 0, 0, 0);
                acc[q][1] = __builtin_amdgcn_mfma_f32_16x16x32_bf16(hfr, wfr[1], acc[q][1], 0, 0, 0);
                acc[q][2] = __builtin_amdgcn_mfma_f32_16x16x32_bf16(hfr, wfr[2], acc[q][2], 0, 0, 0);
                acc[q][3] = __builtin_amdgcn_mfma_f32_16x16x32_bf16(hfr, wfr[3], acc[q][3], 0, 0, 0);
            }
        }
    }

    const size_t outn = (size_t)n * 480000;
    const int base = t0 * 25;
    const int vcols = (7500 - base < 200) ? (7500 - base) : 200;
    #pragma unroll
    for (int q = 0; q < 4; ++q) {
        if (q < nMf) {
            const int col0 = (q * 4 + wv) * 16 + g * 4;
            if (col0 < vcols) {
                #pragma unroll
                for (int mf = 0; mf < 4; ++mf) {
                    const int fo = mf * 16 + l15;
                    const size_t ga = outn + (size_t)fo * 7500 + base + col0;
                    const float4 xr = *(const float4*)(x + ga);
                    const float s2 = s2s[fo], b2 = b2s[fo];
                    float4 o;
                    o.x = fmaxf(acc[q][mf][0] * s2 + b2 + xr.x, 0.f);
                    o.y = fmaxf(acc[q][mf][1] * s2 + b2 + xr.y, 0.f);
                    o.z = fmaxf(acc[q][mf][2] * s2 + b2 + xr.z, 0.f);
                    o.w = fmaxf(acc[q][mf][3] * s2 + b2 + xr.w, 0.f);
                    *(float4*)(out + ga) = o;
                }
            }
        }
    }
}

// ---------------------------------------------------------------------------
extern "C" void kernel_launch(void* const* d_in, const int* in_sizes, int n_in,
                              void* d_out, int out_size, void* d_ws, size_t ws_size,
                              hipStream_t stream) {
    const float* x      = (const float*)d_in[0];
    const float* W1     = (const float*)d_in[1];
    const float* b1     = (const float*)d_in[2];
    const float* A      = (const float*)d_in[3];
    const float* gamma1 = (const float*)d_in[4];
    const float* beta1  = (const float*)d_in[5];
    const float* mean1  = (const float*)d_in[6];
    const float* var1   = (const float*)d_in[7];
    const float* Wt     = (const float*)d_in[8];
    const float* bt     = (const float*)d_in[9];
    const float* gamma2 = (const float*)d_in[10];
    const float* beta2  = (const float*)d_in[11];
    const float* mean2  = (const float*)d_in[12];
    const float* var2   = (const float*)d_in[13];
    float* out = (float*)d_out;
    char* ws = (char*)d_ws;

    hipFuncSetAttribute((const void*)k1_fused_xf,
                        hipFuncAttributeMaxDynamicSharedMemorySize, K1_SMEM);
    hipFuncSetAttribute((const void*)k1_fused,
                        hipFuncAttributeMaxDynamicSharedMemorySize, K1_SMEM);
    hipFuncSetAttribute((const void*)k2_mfma,
                        hipFuncAttributeMaxDynamicSharedMemorySize, K2_SMEM);

    const size_t NEED_XF = 124911504;   // full layout incl. xf + x24
    if (ws_size >= NEED_XF) {
        // h2 0; xf 61,440,000; x24 120,422,400; At 122,880,000;
        // W1t 124,723,200; Abf 124,747,776; csA 124,821,504 (end 124,911,504)
        uint32_t* h2u   = (uint32_t*)ws;
        char*     h2b   = ws;
        char*     xfb   = ws + 61440000;
        uint32_t* xfu   = (uint32_t*)xfb;
        uint16_t* x24   = (uint16_t*)(ws + 120422400);
        uint16_t* At_g  = (uint16_t*)(ws + 122880000);
        uint16_t* W1t   = (uint16_t*)(ws + 124723200);
        uint16_t* Abf   = (uint16_t*)(ws + 124747776);
        float*    csA_g = (float*)   (ws + 124821504);

        k0_prep_small<<<280, 256, 0, stream>>>(W1, Wt, A, W1t, Abf, csA_g);
        k0_prep_At<<<3600, 256, 0, stream>>>(A, At_g);
        k0_prep_x<<<dim3(30, 64), 256, 0, stream>>>(x, xfu, x24);
        k1_fused_xf<<<dim3(75, 64), 256, K1_SMEM, stream>>>(
            xfb, x24, At_g, W1t, csA_g, b1, gamma1, beta1, mean1, var1, h2u);
        k2_mfma<<<dim3(38, 64), 256, K2_SMEM, stream>>>(
            h2b, Abf, bt, gamma2, beta2, mean2, var2, x, out);
    } else {
        // R7 layout fallback
        uint32_t* h2u   = (uint32_t*)ws;
        char*     h2b   = ws;
        uint16_t* At_g  = (uint16_t*)(ws + 61440000);
        uint16_t* W1t   = (uint16_t*)(ws + 63283200);
        uint16_t* Abf   = (uint16_t*)(ws + 63307776);
        float*    csA_g = (float*)   (ws + 63381504);

        k0_prep_small<<<280, 256, 0, stream>>>(W1, Wt, A, W1t, Abf, csA_g);
        k0_prep_At<<<3600, 256, 0, stream>>>(A, At_g);
        k1_fused<<<dim3(75, 64), 256, K1_SMEM, stream>>>(
            x, At_g, W1t, csA_g, b1, gamma1, beta1, mean1, var1, h2u);
        k2_mfma<<<dim3(38, 64), 256, K2_SMEM, stream>>>(
            h2b, Abf, bt, gamma2, beta2, mean2, var2, x, out);
    }
}

// Round 9
// 418.162 us; speedup vs baseline: 1.1035x; 1.1035x over previous
//
#include <hip/hip_runtime.h>
#include <hip/hip_bf16.h>
#include <stdint.h>

#define EPS 1e-3f

typedef __attribute__((ext_vector_type(8))) short bf16x8;
typedef __attribute__((ext_vector_type(4))) float f32x4;

__device__ inline uint32_t pk2(float a, float b) {
    __hip_bfloat162 p;
    p.x = __float2bfloat16(a);
    p.y = __float2bfloat16(b);
    return *(uint32_t*)&p;
}

// ---------------------------------------------------------------------------
// k0a: small preps.
//  W1t[f][K'] = bf16(W1[c][k*64+f]),  K' = k*64+c           (12288 elems)
//  Abf[(kb*64+fo)*8+j] = bf16(Wt[dt][fi][fo]), kb*8+j=dt*64+fi (36864 elems)
//  csA_g[k][t*25+w] = sum_v A[k][t][v][w]                    (22500 floats)
// ---------------------------------------------------------------------------
__global__ __launch_bounds__(256) void k0_prep_small(
    const float* __restrict__ W1, const float* __restrict__ Wt,
    const float* __restrict__ A,
    uint16_t* __restrict__ W1t, uint16_t* __restrict__ Abf,
    float* __restrict__ csA_g)
{
    int i = blockIdx.x * 256 + threadIdx.x;
    if (i < 12288) {
        int f = i / 192, Kp = i % 192, k = Kp >> 6, c = Kp & 63;
        __hip_bfloat16 b = __float2bfloat16(W1[c * 192 + k * 64 + f]);
        W1t[i] = *(uint16_t*)&b;
    } else if (i < 49152) {
        int j = i - 12288;
        int jj = j & 7, fo = (j >> 3) & 63, kb = j >> 9;
        int kk = kb * 8 + jj, dt = kk >> 6, fi = kk & 63;
        __hip_bfloat16 b = __float2bfloat16(Wt[(dt * 64 + fi) * 64 + fo]);
        Abf[j] = *(uint16_t*)&b;
    } else if (i < 71652) {
        int j = i - 49152;
        int k = j / 7500, r = j % 7500;
        int t = r / 25, w = r % 25;
        float s = 0.f;
        for (int v = 0; v < 25; ++v)
            s += A[((k * 300 + t) * 25 + v) * 25 + w];
        csA_g[j] = s;
    }
}

// ---------------------------------------------------------------------------
// k0b: At_g[k][t][w32][v32] = bf16(A[k][t][v][w]), zero outside v<25,w<25.
// ---------------------------------------------------------------------------
__global__ __launch_bounds__(256) void k0_prep_At(
    const float* __restrict__ A, uint16_t* __restrict__ At_g)
{
    int i = blockIdx.x * 256 + threadIdx.x;
    if (i < 921600) {
        int v = i & 31, w = (i >> 5) & 31, rest = i >> 10;
        int t = rest % 300, k = rest / 300;
        float val = 0.f;
        if (v < 25 && w < 25)
            val = A[((k * 300 + t) * 25 + v) * 25 + w];
        __hip_bfloat16 b = __float2bfloat16(val);
        At_g[i] = *(uint16_t*)&b;
    }
}

// ---------------------------------------------------------------------------
// k1 v4 "wave-independent": 4 waves/block, each wave owns one t with a
//  PRIVATE 9.6 KB U^T slab ([w 25 rows][K'=192] bf16, XOR-swizzled).
//  No inter-wave barrier after the const stage: GEMM-u -> slab ->
//  lgkmcnt(0) -> GEMM-z -> epilogue, all intra-wave.
// LDS map: slabs 0..38399 (4 x 9600); s1 38400; b1n 38656; b1 38912..39679.
// ---------------------------------------------------------------------------
#define K1_SMEM 39680
__global__ __launch_bounds__(256, 4) void k1_wave(
    const float* __restrict__ x, const uint16_t* __restrict__ At_g,
    const uint16_t* __restrict__ W1t, const float* __restrict__ csA_g,
    const float* __restrict__ b1,
    const float* __restrict__ gamma1, const float* __restrict__ beta1,
    const float* __restrict__ mean1, const float* __restrict__ var1,
    uint32_t* __restrict__ h2u)
{
    extern __shared__ __align__(16) char smem[];
    float* s1s   = (float*)(smem + 38400);
    float* b1ns  = (float*)(smem + 38656);
    float* b1s   = (float*)(smem + 38912);

    const int t0   = blockIdx.x * 4;
    const int n    = blockIdx.y;
    const int tid  = threadIdx.x;
    const int lane = tid & 63, wv = tid >> 6;
    const int l15  = lane & 15, g = lane >> 4;
    const int t    = t0 + wv;                 // 75*4 = 300: no tail
    char* slab = smem + wv * 9600;

    // ---- B-frags for GEMM-u (global, L2-resident) ----
    bf16x8 bfr[6];
    #pragma unroll
    for (int nf = 0; nf < 6; ++nf) {
        const int col = nf * 16 + l15;
        const int k = col >> 5, w = col & 31;
        bfr[nf] = *(const bf16x8*)(At_g + (((k * 300 + t) * 32 + w) * 32 + g * 8));
    }

    // ---- A-frags directly from x: lane reads x[n, c, t, g*8 .. g*8+7] ----
    const float* xb = x + (size_t)n * 480000 + t * 25;
    bf16x8 a[4];
    #pragma unroll
    for (int mf = 0; mf < 4; ++mf) {
        const int c = l15 + 16 * mf;
        const float* xr = xb + (size_t)c * 7500;
        union { bf16x8 v; uint32_t u[4]; } ua;
        if (g < 3) {
            const float* p = xr + g * 8;
            ua.u[0] = pk2(p[0], p[1]);
            ua.u[1] = pk2(p[2], p[3]);
            ua.u[2] = pk2(p[4], p[5]);
            ua.u[3] = pk2(p[6], p[7]);
        } else {            // v = 24 real; v = 25..31 zero (B rows zeroed too)
            ua.u[0] = pk2(xr[24], 0.f);
            ua.u[1] = 0; ua.u[2] = 0; ua.u[3] = 0;
        }
        a[mf] = ua.v;
    }

    // ---- epilogue constants; ONLY barrier in the kernel ----
    if (tid < 64) {
        float rs = rsqrtf(var1[tid] + EPS);
        s1s[tid]  = gamma1[tid] * rs;
        b1ns[tid] = beta1[tid] - gamma1[tid] * mean1[tid] * rs;
    }
    if (tid >= 64 && tid < 256) b1s[tid - 64] = b1[tid - 64];
    __syncthreads();

    // ---- GEMM-u in 2 halves of 3 nf (caps live accumulators at 48 VGPR) ----
    #pragma unroll
    for (int hh = 0; hh < 2; ++hh) {
        f32x4 acc[4][3];
        #pragma unroll
        for (int mf = 0; mf < 4; ++mf)
            #pragma unroll
            for (int nf3 = 0; nf3 < 3; ++nf3)
                acc[mf][nf3] = (f32x4){0.f, 0.f, 0.f, 0.f};

        #pragma unroll
        for (int nf3 = 0; nf3 < 3; ++nf3) {
            const int nf = hh * 3 + nf3;
            acc[0][nf3] = __builtin_amdgcn_mfma_f32_16x16x32_bf16(a[0], bfr[nf], acc[0][nf3], 0, 0, 0);
            acc[1][nf3] = __builtin_amdgcn_mfma_f32_16x16x32_bf16(a[1], bfr[nf], acc[1][nf3], 0, 0, 0);
            acc[2][nf3] = __builtin_amdgcn_mfma_f32_16x16x32_bf16(a[2], bfr[nf], acc[2][nf3], 0, 0, 0);
            acc[3][nf3] = __builtin_amdgcn_mfma_f32_16x16x32_bf16(a[3], bfr[nf], acc[3][nf3], 0, 0, 0);
        }

        // write U^T slab rows: row = w (<25), byte = (k*64+c)*2 ^ ((w&7)<<4)
        #pragma unroll
        for (int nf3 = 0; nf3 < 3; ++nf3) {
            const int col = (hh * 3 + nf3) * 16 + l15;
            const int k = col >> 5, w = col & 31;
            if (w < 25) {
                const int sw = (w & 7) << 4;
                #pragma unroll
                for (int mf = 0; mf < 4; ++mf) {
                    const int c0 = mf * 16 + g * 4;
                    const int off = w * 384 + (((k * 64 + c0) * 2) ^ sw);
                    uint2 val;
                    val.x = pk2(acc[mf][nf3][0], acc[mf][nf3][1]);
                    val.y = pk2(acc[mf][nf3][2], acc[mf][nf3][3]);
                    *(uint2*)(slab + off) = val;
                }
            }
        }
    }

    // intra-wave LDS dependency: drain writes, pin ordering (no barrier)
    asm volatile("s_waitcnt lgkmcnt(0)" ::: "memory");
    __builtin_amdgcn_sched_barrier(0);

    // ---- GEMM-z (this wave's t only): cols w = q*16 + l15 ----
    int wq[2], qaddr[2], qswz[2];
    #pragma unroll
    for (int q = 0; q < 2; ++q) {
        int w = q * 16 + l15;
        wq[q] = w;
        int wc = (w < 25) ? w : 24;           // clamp keeps ds_read in slab
        qaddr[q] = wc * 384;
        qswz[q]  = (wc & 7) << 4;
    }

    f32x4 accz[4][2];
    #pragma unroll
    for (int mf = 0; mf < 4; ++mf)
        #pragma unroll
        for (int q = 0; q < 2; ++q)
            accz[mf][q] = (f32x4){0.f, 0.f, 0.f, 0.f};

    #pragma unroll
    for (int kb = 0; kb < 6; ++kb) {
        bf16x8 az[4];
        #pragma unroll
        for (int mf = 0; mf < 4; ++mf)
            az[mf] = *(const bf16x8*)(W1t + (l15 + 16 * mf) * 192 + kb * 32 + g * 8);
        #pragma unroll
        for (int q = 0; q < 2; ++q) {
            bf16x8 b = *(const bf16x8*)(slab + qaddr[q] + ((kb * 64 + g * 16) ^ qswz[q]));
            accz[0][q] = __builtin_amdgcn_mfma_f32_16x16x32_bf16(az[0], b, accz[0][q], 0, 0, 0);
            accz[1][q] = __builtin_amdgcn_mfma_f32_16x16x32_bf16(az[1], b, accz[1][q], 0, 0, 0);
            accz[2][q] = __builtin_amdgcn_mfma_f32_16x16x32_bf16(az[2], b, accz[2][q], 0, 0, 0);
            accz[3][q] = __builtin_amdgcn_mfma_f32_16x16x32_bf16(az[3], b, accz[3][q], 0, 0, 0);
        }
    }

    // ---- epilogue: +bias(csA), BN1, ReLU, pack bf16, store h2 ----
    const uint32_t tb = (uint32_t)(n * 300 + t);
    #pragma unroll
    for (int q = 0; q < 2; ++q) {
        const int w = wq[q];
        if (w < 25) {
            const int ci = t * 25 + w;
            const float cs0 = csA_g[ci];
            const float cs1 = csA_g[7500 + ci];
            const float cs2 = csA_g[15000 + ci];
            const uint32_t rowbase = tb * 800 + w * 32;
            #pragma unroll
            for (int mf = 0; mf < 4; ++mf) {
                const int f0 = mf * 16 + g * 4;
                float zz[4];
                #pragma unroll
                for (int rg = 0; rg < 4; ++rg) {
                    const int f = f0 + rg;
                    float z = accz[mf][q][rg]
                            + b1s[f] * cs0 + b1s[64 + f] * cs1 + b1s[128 + f] * cs2;
                    z = z * s1s[f] + b1ns[f];
                    zz[rg] = fmaxf(z, 0.f);
                }
                uint2 st;
                st.x = pk2(zz[0], zz[1]);
                st.y = pk2(zz[2], zz[3]);
                *(uint2*)(h2u + rowbase + (f0 >> 1)) = st;
            }
        }
    }
}

// ---------------------------------------------------------------------------
// k2: operand-swapped temporal conv GEMM (unchanged from R7/R8).
// ---------------------------------------------------------------------------
#define K2_SMEM 51712
__global__ __launch_bounds__(256, 3) void k2_mfma(
    const char* __restrict__ h2b,
    const uint16_t* __restrict__ Abf,
    const float* __restrict__ bt,
    const float* __restrict__ gamma2, const float* __restrict__ beta2,
    const float* __restrict__ mean2,  const float* __restrict__ var2,
    const float* __restrict__ x,
    float* __restrict__ out)
{
    extern __shared__ __align__(16) char smem2[];
    char*  lds_h = smem2;
    float* s2s   = (float*)(smem2 + 51200);
    float* b2s   = s2s + 64;

    const int t0  = blockIdx.x * 8;
    const int n   = blockIdx.y;
    const int tid = threadIdx.x;

    if (tid < 64) {
        float rs = rsqrtf(var2[tid] + EPS);
        float s  = gamma2[tid] * rs;
        s2s[tid] = s;
        b2s[tid] = beta2[tid] - gamma2[tid] * mean2[tid] * rs + bt[tid] * s;
    }

    const size_t hn = (size_t)n * 300 * 3200;
    for (int c = tid; c < 3200; c += 256) {
        int rr = c >> 3, c8 = c & 7;
        int trow = rr / 25;
        int w = rr - trow * 25;
        int tg = t0 - 4 + trow;
        int4 v = make_int4(0, 0, 0, 0);
        if (tg >= 0 && tg < 300)
            v = *(const int4*)(h2b + hn + (size_t)tg * 3200 + w * 128 + (c8 << 4));
        int s = c << 4;
        *(int4*)(lds_h + (s ^ (((s >> 7) & 7) << 4))) = v;
    }
    __syncthreads();

    const int wv = tid >> 6, lane = tid & 63;
    const int l15 = lane & 15, g = lane >> 4;
    const int nMf = (wv == 0) ? 4 : 3;

    int rbase[4];
    #pragma unroll
    for (int q = 0; q < 4; ++q) {
        int col = (q * 4 + wv) * 16 + l15;
        rbase[q] = (col < 200) ? col : 199;
    }

    f32x4 acc[4][4];
    #pragma unroll
    for (int q = 0; q < 4; ++q)
        #pragma unroll
        for (int mf = 0; mf < 4; ++mf)
            acc[q][mf] = (f32x4){0.f, 0.f, 0.f, 0.f};

    for (int kk = 0; kk < 18; ++kk) {
        const int dt   = kk >> 1;
        const int half = (kk & 1) << 6;
        const int kb   = kk * 4 + g;
        bf16x8 wfr[4];
        #pragma unroll
        for (int mf = 0; mf < 4; ++mf)
            wfr[mf] = *(const bf16x8*)(Abf + (kb * 64 + l15 + mf * 16) * 8);
        #pragma unroll
        for (int q = 0; q < 4; ++q) {
            if (q < nMf) {
                int r = rbase[q] + 25 * dt;
                int s = (r << 7) + half + (g << 4);
                bf16x8 hfr = *(const bf16x8*)(lds_h + (s ^ ((r & 7) << 4)));
                acc[q][0] = __builtin_amdgcn_mfma_f32_16x16x32_bf16(hfr, wfr[0], acc[q][0], 0, 0, 0);
                acc[q][1] = __builtin_amdgcn_mfma_f32_16x16x32_bf16(hfr, wfr[1], acc[q][1], 0, 0, 0);
                acc[q][2] = __builtin_amdgcn_mfma_f32_16x16x32_bf16(hfr, wfr[2], acc[q][2], 0, 0, 0);
                acc[q][3] = __builtin_amdgcn_mfma_f32_16x16x32_bf16(hfr, wfr[3], acc[q][3], 0, 0, 0);
            }
        }
    }

    const size_t outn = (size_t)n * 480000;
    const int base = t0 * 25;
    const int vcols = (7500 - base < 200) ? (7500 - base) : 200;
    #pragma unroll
    for (int q = 0; q < 4; ++q) {
        if (q < nMf) {
            const int col0 = (q * 4 + wv) * 16 + g * 4;
            if (col0 < vcols) {
                #pragma unroll
                for (int mf = 0; mf < 4; ++mf) {
                    const int fo = mf * 16 + l15;
                    const size_t ga = outn + (size_t)fo * 7500 + base + col0;
                    const float4 xr = *(const float4*)(x + ga);
                    const float s2 = s2s[fo], b2 = b2s[fo];
                    float4 o;
                    o.x = fmaxf(acc[q][mf][0] * s2 + b2 + xr.x, 0.f);
                    o.y = fmaxf(acc[q][mf][1] * s2 + b2 + xr.y, 0.f);
                    o.z = fmaxf(acc[q][mf][2] * s2 + b2 + xr.z, 0.f);
                    o.w = fmaxf(acc[q][mf][3] * s2 + b2 + xr.w, 0.f);
                    *(float4*)(out + ga) = o;
                }
            }
        }
    }
}

// ---------------------------------------------------------------------------
extern "C" void kernel_launch(void* const* d_in, const int* in_sizes, int n_in,
                              void* d_out, int out_size, void* d_ws, size_t ws_size,
                              hipStream_t stream) {
    const float* x      = (const float*)d_in[0];
    const float* W1     = (const float*)d_in[1];
    const float* b1     = (const float*)d_in[2];
    const float* A      = (const float*)d_in[3];
    const float* gamma1 = (const float*)d_in[4];
    const float* beta1  = (const float*)d_in[5];
    const float* mean1  = (const float*)d_in[6];
    const float* var1   = (const float*)d_in[7];
    const float* Wt     = (const float*)d_in[8];
    const float* bt     = (const float*)d_in[9];
    const float* gamma2 = (const float*)d_in[10];
    const float* beta2  = (const float*)d_in[11];
    const float* mean2  = (const float*)d_in[12];
    const float* var2   = (const float*)d_in[13];
    float* out = (float*)d_out;

    // ws layout (bytes) — R7 layout restored:
    //   h2   : 0          .. 61,440,000   bf16 [64][300][25][64]
    //   At_g : 61,440,000 .. 63,283,200   bf16 [3][300][32][32]
    //   W1t  : 63,283,200 .. 63,307,776   bf16 [64][192]
    //   Abf  : 63,307,776 .. 63,381,504   bf16 Wt frags
    //   csA_g: 63,381,504 .. 63,471,504   f32  [3][7500]
    char* ws = (char*)d_ws;
    uint32_t* h2u   = (uint32_t*)ws;
    char*     h2b   = ws;
    uint16_t* At_g  = (uint16_t*)(ws + 61440000);
    uint16_t* W1t   = (uint16_t*)(ws + 63283200);
    uint16_t* Abf   = (uint16_t*)(ws + 63307776);
    float*    csA_g = (float*)   (ws + 63381504);

    hipFuncSetAttribute((const void*)k1_wave,
                        hipFuncAttributeMaxDynamicSharedMemorySize, K1_SMEM);
    hipFuncSetAttribute((const void*)k2_mfma,
                        hipFuncAttributeMaxDynamicSharedMemorySize, K2_SMEM);

    k0_prep_small<<<280, 256, 0, stream>>>(W1, Wt, A, W1t, Abf, csA_g);
    k0_prep_At<<<3600, 256, 0, stream>>>(A, At_g);
    k1_wave<<<dim3(75, 64), 256, K1_SMEM, stream>>>(
        x, At_g, W1t, csA_g, b1, gamma1, beta1, mean1, var1, h2u);
    k2_mfma<<<dim3(38, 64), 256, K2_SMEM, stream>>>(
        h2b, Abf, bt, gamma2, beta2, mean2, var2, x, out);
}

// Round 10
// 402.693 us; speedup vs baseline: 1.1458x; 1.0384x over previous
//
#include <hip/hip_runtime.h>
#include <hip/hip_bf16.h>
#include <stdint.h>

#define EPS 1e-3f

typedef __attribute__((ext_vector_type(8))) short bf16x8;
typedef __attribute__((ext_vector_type(4))) float f32x4;

__device__ inline uint32_t pk2(float a, float b) {
    __hip_bfloat162 p;
    p.x = __float2bfloat16(a);
    p.y = __float2bfloat16(b);
    return *(uint32_t*)&p;
}

// ---------------------------------------------------------------------------
// k0a: small preps (unchanged).
// ---------------------------------------------------------------------------
__global__ __launch_bounds__(256) void k0_prep_small(
    const float* __restrict__ W1, const float* __restrict__ Wt,
    const float* __restrict__ A,
    uint16_t* __restrict__ W1t, uint16_t* __restrict__ Abf,
    float* __restrict__ csA_g)
{
    int i = blockIdx.x * 256 + threadIdx.x;
    if (i < 12288) {
        int f = i / 192, Kp = i % 192, k = Kp >> 6, c = Kp & 63;
        __hip_bfloat16 b = __float2bfloat16(W1[c * 192 + k * 64 + f]);
        W1t[i] = *(uint16_t*)&b;
    } else if (i < 49152) {
        int j = i - 12288;
        int jj = j & 7, fo = (j >> 3) & 63, kb = j >> 9;
        int kk = kb * 8 + jj, dt = kk >> 6, fi = kk & 63;
        __hip_bfloat16 b = __float2bfloat16(Wt[(dt * 64 + fi) * 64 + fo]);
        Abf[j] = *(uint16_t*)&b;
    } else if (i < 71652) {
        int j = i - 49152;
        int k = j / 7500, r = j % 7500;
        int t = r / 25, w = r % 25;
        float s = 0.f;
        for (int v = 0; v < 25; ++v)
            s += A[((k * 300 + t) * 25 + v) * 25 + w];
        csA_g[j] = s;
    }
}

// ---------------------------------------------------------------------------
// k0b: At_g (unchanged).
// ---------------------------------------------------------------------------
__global__ __launch_bounds__(256) void k0_prep_At(
    const float* __restrict__ A, uint16_t* __restrict__ At_g)
{
    int i = blockIdx.x * 256 + threadIdx.x;
    if (i < 921600) {
        int v = i & 31, w = (i >> 5) & 31, rest = i >> 10;
        int t = rest % 300, k = rest / 300;
        float val = 0.f;
        if (v < 25 && w < 25)
            val = A[((k * 300 + t) * 25 + v) * 25 + w];
        __hip_bfloat16 b = __float2bfloat16(val);
        At_g[i] = *(uint16_t*)&b;
    }
}

// ---------------------------------------------------------------------------
// k1 v6 "forced-MLP": wave-independent structure of R9, but ALL independent
//  global loads issued up front into explicit registers and pinned above the
//  consumers with sched_barrier(0); W1t frags rotate-prefetched in the z-loop;
//  csA prefetched before the z-loop. LDS map unchanged (39,680 B, 4 blk/CU).
// ---------------------------------------------------------------------------
#define K1_SMEM 39680
__global__ __launch_bounds__(256, 4) void k1_wave(
    const float* __restrict__ x, const uint16_t* __restrict__ At_g,
    const uint16_t* __restrict__ W1t, const float* __restrict__ csA_g,
    const float* __restrict__ b1,
    const float* __restrict__ gamma1, const float* __restrict__ beta1,
    const float* __restrict__ mean1, const float* __restrict__ var1,
    uint32_t* __restrict__ h2u)
{
    extern __shared__ __align__(16) char smem[];
    float* s1s   = (float*)(smem + 38400);
    float* b1ns  = (float*)(smem + 38656);
    float* b1s   = (float*)(smem + 38912);

    const int t0   = blockIdx.x * 4;
    const int n    = blockIdx.y;
    const int tid  = threadIdx.x;
    const int lane = tid & 63, wv = tid >> 6;
    const int l15  = lane & 15, g = lane >> 4;
    const int t    = t0 + wv;                 // 75*4 = 300: no tail
    char* slab = smem + wv * 9600;

    // ================= PHASE A: issue ALL independent loads =================
    bf16x8 bfr[6];
    #pragma unroll
    for (int nf = 0; nf < 6; ++nf) {
        const int col = nf * 16 + l15;
        const int k = col >> 5, w = col & 31;
        bfr[nf] = *(const bf16x8*)(At_g + (((k * 300 + t) * 32 + w) * 32 + g * 8));
    }

    const float* xb = x + (size_t)n * 480000 + t * 25;
    float xr8[4][8];
    float x24v[4];
    #pragma unroll
    for (int mf = 0; mf < 4; ++mf) {
        const int c = l15 + 16 * mf;
        const float* xr = xb + (size_t)c * 7500;
        if (g < 3) {
            const float* p = xr + g * 8;
            #pragma unroll
            for (int j = 0; j < 8; ++j) xr8[mf][j] = p[j];
        } else {
            x24v[mf] = xr[24];
        }
    }

    // csA for epilogue (w = q*16+l15 valid only when < 25)
    float cs[2][3];
    #pragma unroll
    for (int q = 0; q < 2; ++q) {
        const int w = q * 16 + l15;
        const int wc = (w < 25) ? w : 24;     // clamp: in-bounds dummy
        const int ci = t * 25 + wc;
        cs[q][0] = csA_g[ci];
        cs[q][1] = csA_g[7500 + ci];
        cs[q][2] = csA_g[15000 + ci];
    }

    // pin every load above all consumers
    __builtin_amdgcn_sched_barrier(0);

    // ---- epilogue constants; only barrier in the kernel ----
    if (tid < 64) {
        float rs = rsqrtf(var1[tid] + EPS);
        s1s[tid]  = gamma1[tid] * rs;
        b1ns[tid] = beta1[tid] - gamma1[tid] * mean1[tid] * rs;
    }
    if (tid >= 64 && tid < 256) b1s[tid - 64] = b1[tid - 64];
    __syncthreads();

    // ================= convert x to A-frags =================
    bf16x8 a[4];
    #pragma unroll
    for (int mf = 0; mf < 4; ++mf) {
        union { bf16x8 v; uint32_t u[4]; } ua;
        if (g < 3) {
            ua.u[0] = pk2(xr8[mf][0], xr8[mf][1]);
            ua.u[1] = pk2(xr8[mf][2], xr8[mf][3]);
            ua.u[2] = pk2(xr8[mf][4], xr8[mf][5]);
            ua.u[3] = pk2(xr8[mf][6], xr8[mf][7]);
        } else {
            ua.u[0] = pk2(x24v[mf], 0.f);
            ua.u[1] = 0; ua.u[2] = 0; ua.u[3] = 0;
        }
        a[mf] = ua.v;
    }

    // ================= GEMM-u (2 halves of 3 nf) -> slab =================
    #pragma unroll
    for (int hh = 0; hh < 2; ++hh) {
        f32x4 acc[4][3];
        #pragma unroll
        for (int mf = 0; mf < 4; ++mf)
            #pragma unroll
            for (int nf3 = 0; nf3 < 3; ++nf3)
                acc[mf][nf3] = (f32x4){0.f, 0.f, 0.f, 0.f};

        #pragma unroll
        for (int nf3 = 0; nf3 < 3; ++nf3) {
            const int nf = hh * 3 + nf3;
            acc[0][nf3] = __builtin_amdgcn_mfma_f32_16x16x32_bf16(a[0], bfr[nf], acc[0][nf3], 0, 0, 0);
            acc[1][nf3] = __builtin_amdgcn_mfma_f32_16x16x32_bf16(a[1], bfr[nf], acc[1][nf3], 0, 0, 0);
            acc[2][nf3] = __builtin_amdgcn_mfma_f32_16x16x32_bf16(a[2], bfr[nf], acc[2][nf3], 0, 0, 0);
            acc[3][nf3] = __builtin_amdgcn_mfma_f32_16x16x32_bf16(a[3], bfr[nf], acc[3][nf3], 0, 0, 0);
        }

        #pragma unroll
        for (int nf3 = 0; nf3 < 3; ++nf3) {
            const int col = (hh * 3 + nf3) * 16 + l15;
            const int k = col >> 5, w = col & 31;
            if (w < 25) {
                const int sw = (w & 7) << 4;
                #pragma unroll
                for (int mf = 0; mf < 4; ++mf) {
                    const int c0 = mf * 16 + g * 4;
                    const int off = w * 384 + (((k * 64 + c0) * 2) ^ sw);
                    uint2 val;
                    val.x = pk2(acc[mf][nf3][0], acc[mf][nf3][1]);
                    val.y = pk2(acc[mf][nf3][2], acc[mf][nf3][3]);
                    *(uint2*)(slab + off) = val;
                }
            }
        }
    }

    // prefetch W1t kb=0 while LDS drains (independent of LDS)
    bf16x8 azc[4];
    #pragma unroll
    for (int mf = 0; mf < 4; ++mf)
        azc[mf] = *(const bf16x8*)(W1t + (l15 + 16 * mf) * 192 + g * 8);

    // intra-wave LDS dependency: drain writes, pin ordering (no barrier)
    asm volatile("s_waitcnt lgkmcnt(0)" ::: "memory");
    __builtin_amdgcn_sched_barrier(0);

    // ================= GEMM-z with W1t rotation =================
    int wq[2], qaddr[2], qswz[2];
    #pragma unroll
    for (int q = 0; q < 2; ++q) {
        int w = q * 16 + l15;
        wq[q] = w;
        int wc = (w < 25) ? w : 24;
        qaddr[q] = wc * 384;
        qswz[q]  = (wc & 7) << 4;
    }

    f32x4 accz[4][2];
    #pragma unroll
    for (int mf = 0; mf < 4; ++mf)
        #pragma unroll
        for (int q = 0; q < 2; ++q)
            accz[mf][q] = (f32x4){0.f, 0.f, 0.f, 0.f};

    #pragma unroll
    for (int kb = 0; kb < 6; ++kb) {
        bf16x8 azn[4];
        if (kb < 5) {
            #pragma unroll
            for (int mf = 0; mf < 4; ++mf)
                azn[mf] = *(const bf16x8*)(W1t + (l15 + 16 * mf) * 192 + (kb + 1) * 32 + g * 8);
        }
        #pragma unroll
        for (int q = 0; q < 2; ++q) {
            bf16x8 b = *(const bf16x8*)(slab + qaddr[q] + ((kb * 64 + g * 16) ^ qswz[q]));
            accz[0][q] = __builtin_amdgcn_mfma_f32_16x16x32_bf16(azc[0], b, accz[0][q], 0, 0, 0);
            accz[1][q] = __builtin_amdgcn_mfma_f32_16x16x32_bf16(azc[1], b, accz[1][q], 0, 0, 0);
            accz[2][q] = __builtin_amdgcn_mfma_f32_16x16x32_bf16(azc[2], b, accz[2][q], 0, 0, 0);
            accz[3][q] = __builtin_amdgcn_mfma_f32_16x16x32_bf16(azc[3], b, accz[3][q], 0, 0, 0);
        }
        if (kb < 5) {
            #pragma unroll
            for (int mf = 0; mf < 4; ++mf) azc[mf] = azn[mf];
        }
    }

    // ================= epilogue =================
    const uint32_t tb = (uint32_t)(n * 300 + t);
    #pragma unroll
    for (int q = 0; q < 2; ++q) {
        const int w = wq[q];
        if (w < 25) {
            const uint32_t rowbase = tb * 800 + w * 32;
            #pragma unroll
            for (int mf = 0; mf < 4; ++mf) {
                const int f0 = mf * 16 + g * 4;
                float zz[4];
                #pragma unroll
                for (int rg = 0; rg < 4; ++rg) {
                    const int f = f0 + rg;
                    float z = accz[mf][q][rg]
                            + b1s[f] * cs[q][0] + b1s[64 + f] * cs[q][1]
                            + b1s[128 + f] * cs[q][2];
                    z = z * s1s[f] + b1ns[f];
                    zz[rg] = fmaxf(z, 0.f);
                }
                uint2 st;
                st.x = pk2(zz[0], zz[1]);
                st.y = pk2(zz[2], zz[3]);
                *(uint2*)(h2u + rowbase + (f0 >> 1)) = st;
            }
        }
    }
}

// ---------------------------------------------------------------------------
// k2 v3: operand-swapped temporal conv GEMM + forced-MLP staging, Wt-frag
//  rotation in the kk loop, and batched epilogue x-loads.
// ---------------------------------------------------------------------------
#define K2_SMEM 51712
__global__ __launch_bounds__(256, 3) void k2_mfma(
    const char* __restrict__ h2b,
    const uint16_t* __restrict__ Abf,
    const float* __restrict__ bt,
    const float* __restrict__ gamma2, const float* __restrict__ beta2,
    const float* __restrict__ mean2,  const float* __restrict__ var2,
    const float* __restrict__ x,
    float* __restrict__ out)
{
    extern __shared__ __align__(16) char smem2[];
    char*  lds_h = smem2;
    float* s2s   = (float*)(smem2 + 51200);
    float* b2s   = s2s + 64;

    const int t0  = blockIdx.x * 8;
    const int n   = blockIdx.y;
    const int tid = threadIdx.x;

    // ---- stage h tile: issue ALL 13 loads first, then write LDS ----
    const size_t hn = (size_t)n * 300 * 3200;
    int4 tmp[13];
    #pragma unroll
    for (int i = 0; i < 13; ++i) {
        const int c = tid + i * 256;
        tmp[i] = make_int4(0, 0, 0, 0);
        if (c < 3200) {
            int rr = c >> 3, c8 = c & 7;
            int trow = rr / 25;
            int w = rr - trow * 25;
            int tg = t0 - 4 + trow;
            if (tg >= 0 && tg < 300)
                tmp[i] = *(const int4*)(h2b + hn + (size_t)tg * 3200 + w * 128 + (c8 << 4));
        }
    }
    __builtin_amdgcn_sched_barrier(0);

    if (tid < 64) {
        float rs = rsqrtf(var2[tid] + EPS);
        float s  = gamma2[tid] * rs;
        s2s[tid] = s;
        b2s[tid] = beta2[tid] - gamma2[tid] * mean2[tid] * rs + bt[tid] * s;
    }

    #pragma unroll
    for (int i = 0; i < 13; ++i) {
        const int c = tid + i * 256;
        if (c < 3200) {
            int s = c << 4;
            *(int4*)(lds_h + (s ^ (((s >> 7) & 7) << 4))) = tmp[i];
        }
    }
    __syncthreads();

    const int wv = tid >> 6, lane = tid & 63;
    const int l15 = lane & 15, g = lane >> 4;
    const int nMf = (wv == 0) ? 4 : 3;

    int rbase[4];
    #pragma unroll
    for (int q = 0; q < 4; ++q) {
        int col = (q * 4 + wv) * 16 + l15;
        rbase[q] = (col < 200) ? col : 199;
    }

    f32x4 acc[4][4];
    #pragma unroll
    for (int q = 0; q < 4; ++q)
        #pragma unroll
        for (int mf = 0; mf < 4; ++mf)
            acc[q][mf] = (f32x4){0.f, 0.f, 0.f, 0.f};

    // Wt frag rotation: preload kk=0
    bf16x8 wc_[4];
    #pragma unroll
    for (int mf = 0; mf < 4; ++mf)
        wc_[mf] = *(const bf16x8*)(Abf + ((0 * 4 + g) * 64 + l15 + mf * 16) * 8);

    for (int kk = 0; kk < 18; ++kk) {
        const int dt   = kk >> 1;
        const int half = (kk & 1) << 6;
        bf16x8 wn_[4];
        if (kk < 17) {
            const int kbn = (kk + 1) * 4 + g;
            #pragma unroll
            for (int mf = 0; mf < 4; ++mf)
                wn_[mf] = *(const bf16x8*)(Abf + (kbn * 64 + l15 + mf * 16) * 8);
        }
        #pragma unroll
        for (int q = 0; q < 4; ++q) {
            if (q < nMf) {
                int r = rbase[q] + 25 * dt;
                int s = (r << 7) + half + (g << 4);
                bf16x8 hfr = *(const bf16x8*)(lds_h + (s ^ ((r & 7) << 4)));
                acc[q][0] = __builtin_amdgcn_mfma_f32_16x16x32_bf16(hfr, wc_[0], acc[q][0], 0, 0, 0);
                acc[q][1] = __builtin_amdgcn_mfma_f32_16x16x32_bf16(hfr, wc_[1], acc[q][1], 0, 0, 0);
                acc[q][2] = __builtin_amdgcn_mfma_f32_16x16x32_bf16(hfr, wc_[2], acc[q][2], 0, 0, 0);
                acc[q][3] = __builtin_amdgcn_mfma_f32_16x16x32_bf16(hfr, wc_[3], acc[q][3], 0, 0, 0);
            }
        }
        if (kk < 17) {
            #pragma unroll
            for (int mf = 0; mf < 4; ++mf) wc_[mf] = wn_[mf];
        }
    }

    // ---- epilogue: batch all residual x loads, then compute + store ----
    const size_t outn = (size_t)n * 480000;
    const int base = t0 * 25;
    const int vcols = (7500 - base < 200) ? (7500 - base) : 200;

    float4 xrv[4][4];
    #pragma unroll
    for (int q = 0; q < 4; ++q) {
        const int col0 = (q * 4 + wv) * 16 + g * 4;
        if (q < nMf && col0 < vcols) {
            #pragma unroll
            for (int mf = 0; mf < 4; ++mf) {
                const int fo = mf * 16 + l15;
                xrv[q][mf] = *(const float4*)(x + outn + (size_t)fo * 7500 + base + col0);
            }
        }
    }
    __builtin_amdgcn_sched_barrier(0);

    #pragma unroll
    for (int q = 0; q < 4; ++q) {
        const int col0 = (q * 4 + wv) * 16 + g * 4;
        if (q < nMf && col0 < vcols) {
            #pragma unroll
            for (int mf = 0; mf < 4; ++mf) {
                const int fo = mf * 16 + l15;
                const size_t ga = outn + (size_t)fo * 7500 + base + col0;
                const float s2 = s2s[fo], b2 = b2s[fo];
                float4 o;
                o.x = fmaxf(acc[q][mf][0] * s2 + b2 + xrv[q][mf].x, 0.f);
                o.y = fmaxf(acc[q][mf][1] * s2 + b2 + xrv[q][mf].y, 0.f);
                o.z = fmaxf(acc[q][mf][2] * s2 + b2 + xrv[q][mf].z, 0.f);
                o.w = fmaxf(acc[q][mf][3] * s2 + b2 + xrv[q][mf].w, 0.f);
                *(float4*)(out + ga) = o;
            }
        }
    }
}

// ---------------------------------------------------------------------------
extern "C" void kernel_launch(void* const* d_in, const int* in_sizes, int n_in,
                              void* d_out, int out_size, void* d_ws, size_t ws_size,
                              hipStream_t stream) {
    const float* x      = (const float*)d_in[0];
    const float* W1     = (const float*)d_in[1];
    const float* b1     = (const float*)d_in[2];
    const float* A      = (const float*)d_in[3];
    const float* gamma1 = (const float*)d_in[4];
    const float* beta1  = (const float*)d_in[5];
    const float* mean1  = (const float*)d_in[6];
    const float* var1   = (const float*)d_in[7];
    const float* Wt     = (const float*)d_in[8];
    const float* bt     = (const float*)d_in[9];
    const float* gamma2 = (const float*)d_in[10];
    const float* beta2  = (const float*)d_in[11];
    const float* mean2  = (const float*)d_in[12];
    const float* var2   = (const float*)d_in[13];
    float* out = (float*)d_out;

    // ws layout (bytes):
    //   h2   : 0          .. 61,440,000   bf16 [64][300][25][64]
    //   At_g : 61,440,000 .. 63,283,200   bf16 [3][300][32][32]
    //   W1t  : 63,283,200 .. 63,307,776   bf16 [64][192]
    //   Abf  : 63,307,776 .. 63,381,504   bf16 Wt frags
    //   csA_g: 63,381,504 .. 63,471,504   f32  [3][7500]
    char* ws = (char*)d_ws;
    uint32_t* h2u   = (uint32_t*)ws;
    char*     h2b   = ws;
    uint16_t* At_g  = (uint16_t*)(ws + 61440000);
    uint16_t* W1t   = (uint16_t*)(ws + 63283200);
    uint16_t* Abf   = (uint16_t*)(ws + 63307776);
    float*    csA_g = (float*)   (ws + 63381504);

    hipFuncSetAttribute((const void*)k1_wave,
                        hipFuncAttributeMaxDynamicSharedMemorySize, K1_SMEM);
    hipFuncSetAttribute((const void*)k2_mfma,
                        hipFuncAttributeMaxDynamicSharedMemorySize, K2_SMEM);

    k0_prep_small<<<280, 256, 0, stream>>>(W1, Wt, A, W1t, Abf, csA_g);
    k0_prep_At<<<3600, 256, 0, stream>>>(A, At_g);
    k1_wave<<<dim3(75, 64), 256, K1_SMEM, stream>>>(
        x, At_g, W1t, csA_g, b1, gamma1, beta1, mean1, var1, h2u);
    k2_mfma<<<dim3(38, 64), 256, K2_SMEM, stream>>>(
        h2b, Abf, bt, gamma2, beta2, mean2, var2, x, out);
}